// Round 6
// baseline (324.723 us; speedup 1.0000x reference)
//
#include <hip/hip_runtime.h>
#include <stdint.h>

// Problem constants (B=64, S=512 -> 32768 tokens)
#define N_TOK 32768
#define DIN   512
#define DFF   1024
#define MPAD  33792   // 32768 + 8*128 worst-case bucket padding

// fp8 LDS tile: 128 rows x 136 B (128 data + 8 pad). Bank step/row = 34 = 2 mod 32
// -> every 16-lane quarter-wave 8B read covers all 32 banks once: conflict-free.
#define TSTRIDE 136
#define TBYTES  (128 * TSTRIDE)          // 17408
#define TCHUNKS (TBYTES / 16)            // 1088

typedef __attribute__((ext_vector_type(8))) short bf16x8;
typedef __attribute__((ext_vector_type(4))) float f32x4;

__device__ __forceinline__ unsigned short f2bf(float f) {
    union { float f; unsigned int u; } v; v.f = f;
    unsigned int u = v.u;
    return (unsigned short)((u + 0x7FFFu + ((u >> 16) & 1u)) >> 16);
}
__device__ __forceinline__ float bf2f(unsigned int bits) {
    union { unsigned int u; float f; } v; v.u = bits << 16; return v.f;
}
// pack 4 floats -> 4 OCP e4m3 bytes (hw cvt, saturating)
__device__ __forceinline__ unsigned int pk4_fp8(float a, float b, float c, float d) {
    int v = __builtin_amdgcn_cvt_pk_fp8_f32(a, b, 0, false);
    v = __builtin_amdgcn_cvt_pk_fp8_f32(c, d, v, true);
    return (unsigned int)v;
}
__device__ __forceinline__ unsigned char f2fp8(float a) {
    return (unsigned char)(__builtin_amdgcn_cvt_pk_fp8_f32(a, a, 0, false) & 0xFF);
}

// async 16B global -> LDS (wave-uniform LDS base + lane*16 pattern)
__device__ __forceinline__ void async16(const void* g, void* l) {
    __builtin_amdgcn_global_load_lds(
        (const __attribute__((address_space(1))) void*)g,
        (__attribute__((address_space(3))) void*)l, 16, 0, 0);
}

// ---------------- fused weight prep ----------------
// z=0: W_pre [512][1024] -> Wp8 [1024][512] fp8 (x64)
// z=1..8: W_types[z-1] [1024][512] -> Wt8 [512][1024] fp8 (x64)
// z=9: W_c1 [512][512] -> WcT bf16 [512][512]
// also zeroes cnt[0..7] and fill2 (=cnt[8..15])
__global__ void prep_weights_kernel(const float* __restrict__ Wp,
                                    const float* __restrict__ Wt,
                                    const float* __restrict__ Wc,
                                    unsigned char* __restrict__ Wp8,
                                    unsigned char* __restrict__ Wt8,
                                    unsigned short* __restrict__ WcT,
                                    int* __restrict__ cnt) {
    __shared__ float tile[32][33];
    const int z = blockIdx.z;
    if (z == 0 && blockIdx.x == 0 && blockIdx.y == 0 &&
        threadIdx.y == 0 && threadIdx.x < 16)
        cnt[threadIdx.x] = 0;
    const float* s; int K, N;
    if (z == 0)      { s = Wp;                          K = 512;  N = 1024; }
    else if (z <= 8) { s = Wt + (size_t)(z-1)*DIN*DFF;  K = 1024; N = 512; }
    else             { s = Wc;                          K = 512;  N = 512; }
    const int n0 = blockIdx.x * 32, k0 = blockIdx.y * 32;
    if (n0 >= N || k0 >= K) return;
    for (int i = threadIdx.y; i < 32; i += 8)
        tile[i][threadIdx.x] = s[(size_t)(k0 + i) * N + n0 + threadIdx.x];
    __syncthreads();
    if (z == 0) {
        for (int i = threadIdx.y; i < 32; i += 8)
            Wp8[(size_t)(n0 + i) * K + k0 + threadIdx.x] = f2fp8(tile[threadIdx.x][i] * 64.f);
    } else if (z <= 8) {
        unsigned char* d = Wt8 + (size_t)(z-1)*DIN*DFF;
        for (int i = threadIdx.y; i < 32; i += 8)
            d[(size_t)(n0 + i) * K + k0 + threadIdx.x] = f2fp8(tile[threadIdx.x][i] * 64.f);
    } else {
        for (int i = threadIdx.y; i < 32; i += 8)
            WcT[(size_t)(n0 + i) * K + k0 + threadIdx.x] = f2bf(tile[threadIdx.x][i]);
    }
}

// ---------------- fused token prep: x -> bf16 Xb + fp8 Xb8, histogram, perm init --
__global__ void prep_tokens_kernel(const float* __restrict__ x,
                                   unsigned short* __restrict__ Xb,
                                   unsigned char* __restrict__ Xb8,
                                   const int* __restrict__ types,
                                   int* __restrict__ cnt,
                                   int* __restrict__ perm) {
    __shared__ int lc[8];
    const int blk = blockIdx.x, tid = threadIdx.x;
    const int i = blk * 1024 + tid * 4;
    float4 v = *(const float4*)(x + i);
    ushort4 o;
    o.x = f2bf(v.x); o.y = f2bf(v.y); o.z = f2bf(v.z); o.w = f2bf(v.w);
    *(ushort4*)(Xb + i) = o;
    *(unsigned int*)(Xb8 + i) = pk4_fp8(v.x, v.y, v.z, v.w);
    if (blk < 64) {
        if (tid < 8) lc[tid] = 0;
        __syncthreads();
        atomicAdd(&lc[types[blk * 512 + tid]], 1);
        atomicAdd(&lc[types[blk * 512 + 256 + tid]], 1);
        __syncthreads();
        if (tid < 8) atomicAdd(&cnt[tid], lc[tid]);
    } else if (blk < 64 + MPAD / 256) {
        perm[(blk - 64) * 256 + tid] = -1;
    }
}

// scatter token ids into buckets (prefix computed locally from cnt); zero out[]
__global__ void scatter_kernel(const int* __restrict__ types,
                               const int* __restrict__ cnt,
                               int* __restrict__ fill2,
                               int* __restrict__ perm,
                               float* __restrict__ outz) {
    int i = blockIdx.x * 256 + threadIdx.x;      // grid exactly covers N_TOK
    outz[i] = 0.f;
    int pob[8]; int off = 0;
    #pragma unroll
    for (int b = 0; b < 8; b++) { pob[b] = off; off += ((cnt[b] + 127) >> 7) << 7; }
    int lane = threadIdx.x & 63;
    unsigned long long lt = (1ull << lane) - 1ull;
    int t = types[i];
    #pragma unroll
    for (int b = 0; b < 8; b++) {
        unsigned long long m = __ballot(t == b);
        if (t == b) {
            int leader = __ffsll((unsigned long long)m) - 1;
            int base = 0;
            if (lane == leader) base = atomicAdd(&fill2[b], __popcll(m));
            base = __shfl(base, leader);
            perm[pob[b] + base + __popcll(m & lt)] = i;
        }
    }
}

// ---------- fp8 GEMM: 128x128 tile, BK=128, 256 thr / 4 waves, 16x16x32 fp8 -----
// LDS tiles use 136B row stride (conflict-free, see TSTRIDE). Staging chunk at
// LDS offset o sources global row (o+8)/136, col o-136*row (straddle chunks
// read rowstart-8: 16 contiguous global bytes; 8 stale bytes land in the pad).
// D[n][tok] via swapped operands: n = quad*4+reg, tok = lane&15.
// MODE 0 (GEMM1): C = fp8(relu(acc) * 0.125)   [= 8*x_, acc carries x64 from W]
// MODE 1 (GEMM2): rows gathered via perm, B per bucket (prefix from cnt);
//                 C_bf16[tok] = bf16(xres_bf16[tok] + relu(acc)/512)
template <int MODE>
__global__ __launch_bounds__(256, 4)
void gemm_fp8_kernel(const unsigned char* __restrict__ A,
                     const unsigned char* __restrict__ B,
                     void* __restrict__ Cout,
                     const unsigned short* __restrict__ xres,
                     const int* __restrict__ perm,
                     const int* __restrict__ cnt,
                     int K, int ldA) {
    __shared__ unsigned char As[TBYTES];
    __shared__ unsigned char Bs[TBYTES];
    __shared__ int perm_tile[128];

    const int tid  = threadIdx.x;
    const int wave = tid >> 6;
    const int lane = tid & 63;
    const int quad = lane >> 4;
    const int tl   = lane & 15;
    const int m0 = blockIdx.y * 128;
    const int n0 = blockIdx.x * 128;
    const int wm = (wave & 1) * 64;
    const int wn = (wave >> 1) * 64;

    const unsigned char* Bp = B;
    if constexpr (MODE == 1) {
        int bsel = 0, total = 0;
        #pragma unroll
        for (int i = 0; i < 8; i++) {
            if (i > 0 && m0 >= total) bsel = i;   // total == po[i] at loop top
            total += ((cnt[i] + 127) >> 7) << 7;
        }
        if (m0 >= total) return;                  // fully-padded tail block
        Bp = B + (size_t)bsel * (DIN * DFF);
        if (tid < 128) perm_tile[tid] = perm[m0 + tid];
    }

    f32x4 acc[4][4];
    #pragma unroll
    for (int i = 0; i < 4; i++)
        #pragma unroll
        for (int j = 0; j < 4; j++)
            acc[i][j] = (f32x4){0.f, 0.f, 0.f, 0.f};

    for (int k0 = 0; k0 < K; k0 += 128) {
        __syncthreads();
        // A tile: 1088 chunks of 16B over 256 threads (5 groups, last wave-masked)
        #pragma unroll
        for (int g = 0; g < 5; g++) {
            const int c = g * 256 + tid;
            if (c < TCHUNKS) {
                const int o   = c * 16;
                const int row = (o + 8) / TSTRIDE;
                const int col = o - row * TSTRIDE;      // -8 for straddle chunks
                size_t arow;
                if constexpr (MODE == 1) {
                    int tok = perm_tile[row];
                    arow = (size_t)(tok < 0 ? 0 : tok);
                } else {
                    arow = (size_t)(m0 + row);
                }
                async16(A + arow * ldA + k0 + col, (char*)As + o);
            }
        }
        // B tile, same scheme
        #pragma unroll
        for (int g = 0; g < 5; g++) {
            const int c = g * 256 + tid;
            if (c < TCHUNKS) {
                const int o   = c * 16;
                const int row = (o + 8) / TSTRIDE;
                const int col = o - row * TSTRIDE;
                async16(Bp + (size_t)(n0 + row) * K + k0 + col, (char*)Bs + o);
            }
        }
        __syncthreads();

        #pragma unroll
        for (int ks = 0; ks < 4; ks++) {
            long af[4], bfr[4];
            const int kb = ks * 32 + quad * 8;       // fragment byte offset in row
            #pragma unroll
            for (int t = 0; t < 4; t++)
                af[t] = *(const long*)(As + (wm + t * 16 + tl) * TSTRIDE + kb);
            #pragma unroll
            for (int t = 0; t < 4; t++)
                bfr[t] = *(const long*)(Bs + (wn + t * 16 + tl) * TSTRIDE + kb);
            #pragma unroll
            for (int mt = 0; mt < 4; mt++)
                #pragma unroll
                for (int nt = 0; nt < 4; nt++)
                    acc[mt][nt] = __builtin_amdgcn_mfma_f32_16x16x32_fp8_fp8(
                        bfr[nt], af[mt], acc[mt][nt], 0, 0, 0);  // swapped: D[n][tok]
        }
    }

    // epilogue: lane holds 4 consecutive n (regs) for token tl
    if constexpr (MODE == 0) {
        unsigned char* C8 = (unsigned char*)Cout;
        #pragma unroll
        for (int mt = 0; mt < 4; mt++) {
            const size_t rowbase = (size_t)(m0 + wm + mt * 16 + tl) * DFF;
            #pragma unroll
            for (int nt = 0; nt < 4; nt++) {
                const int ncol = n0 + wn + nt * 16 + quad * 4;
                unsigned int p = pk4_fp8(fmaxf(acc[mt][nt][0], 0.f) * 0.125f,
                                         fmaxf(acc[mt][nt][1], 0.f) * 0.125f,
                                         fmaxf(acc[mt][nt][2], 0.f) * 0.125f,
                                         fmaxf(acc[mt][nt][3], 0.f) * 0.125f);
                *(unsigned int*)(C8 + rowbase + ncol) = p;
            }
        }
    } else {
        unsigned short* Cb = (unsigned short*)Cout;
        #pragma unroll
        for (int mt = 0; mt < 4; mt++) {
            int tok = perm_tile[wm + mt * 16 + tl];
            if (tok < 0) continue;
            const size_t rowbase = (size_t)tok * DIN;
            #pragma unroll
            for (int nt = 0; nt < 4; nt++) {
                const int ncol = n0 + wn + nt * 16 + quad * 4;
                ushort4 rv = *(const ushort4*)(xres + rowbase + ncol);
                ushort4 o;
                o.x = f2bf(bf2f(rv.x) + fmaxf(acc[mt][nt][0], 0.f) * 0.001953125f);
                o.y = f2bf(bf2f(rv.y) + fmaxf(acc[mt][nt][1], 0.f) * 0.001953125f);
                o.z = f2bf(bf2f(rv.z) + fmaxf(acc[mt][nt][2], 0.f) * 0.001953125f);
                o.w = f2bf(bf2f(rv.w) + fmaxf(acc[mt][nt][3], 0.f) * 0.001953125f);
                *(ushort4*)(Cb + rowbase + ncol) = o;
            }
        }
    }
}

// ------- bf16 GEMM3 + head (kept full precision): 128x256 tile, 512 thr --------
// out[tok] += relu(Xb @ W_c1) . w2   (atomicAdd partials per n-block)
__global__ __launch_bounds__(512, 4)
void gemm3_kernel(const unsigned short* __restrict__ A,
                  const unsigned short* __restrict__ B,
                  const float* __restrict__ w2,
                  float* __restrict__ outp,
                  int K, int ldA) {
    __shared__ unsigned short As[128 * 64];
    __shared__ unsigned short Bs[256 * 64];

    const int tid  = threadIdx.x;
    const int wave = tid >> 6;
    const int lane = tid & 63;
    const int quad = lane >> 4;
    const int tl   = lane & 15;
    const int m0 = blockIdx.y * 128;
    const int n0 = blockIdx.x * 256;
    const int wm = (wave & 1) * 64;
    const int wn = (wave >> 1) * 64;

    f32x4 acc[4][4];
    #pragma unroll
    for (int i = 0; i < 4; i++)
        #pragma unroll
        for (int j = 0; j < 4; j++)
            acc[i][j] = (f32x4){0.f, 0.f, 0.f, 0.f};

    for (int k0 = 0; k0 < K; k0 += 64) {
        __syncthreads();
        #pragma unroll
        for (int i = 0; i < 2; i++) {
            const int c   = (i * 8 + wave) * 64 + lane;
            const int row = c >> 3;
            const int gj  = (c & 7) ^ (row & 7);
            async16(A + (size_t)(m0 + row) * ldA + k0 + gj * 8, (char*)As + (size_t)c * 16);
        }
        #pragma unroll
        for (int i = 0; i < 4; i++) {
            const int c   = (i * 8 + wave) * 64 + lane;
            const int row = c >> 3;
            const int gj  = (c & 7) ^ (row & 7);
            async16(B + (size_t)(n0 + row) * K + k0 + gj * 8, (char*)Bs + (size_t)c * 16);
        }
        __syncthreads();

        #pragma unroll
        for (int ks = 0; ks < 2; ks++) {
            bf16x8 af[4], bfr[4];
            const int jc = ks * 4 + quad;
            #pragma unroll
            for (int t = 0; t < 4; t++) {
                const int r = wm + t * 16 + tl;
                af[t] = *(const bf16x8*)(As + (r * 8 + (jc ^ (r & 7))) * 8);
            }
            #pragma unroll
            for (int t = 0; t < 4; t++) {
                const int r = wn + t * 16 + tl;
                bfr[t] = *(const bf16x8*)(Bs + (r * 8 + (jc ^ (r & 7))) * 8);
            }
            #pragma unroll
            for (int mt = 0; mt < 4; mt++)
                #pragma unroll
                for (int nt = 0; nt < 4; nt++)
                    acc[mt][nt] = __builtin_amdgcn_mfma_f32_16x16x32_bf16(
                        bfr[nt], af[mt], acc[mt][nt], 0, 0, 0);
        }
    }

    float4 w2v[4];
    #pragma unroll
    for (int nt = 0; nt < 4; nt++)
        w2v[nt] = *(const float4*)(w2 + n0 + wn + nt * 16 + quad * 4);
    #pragma unroll
    for (int mt = 0; mt < 4; mt++) {
        float s = 0.f;
        #pragma unroll
        for (int nt = 0; nt < 4; nt++) {
            s += fmaxf(acc[mt][nt][0], 0.f) * w2v[nt].x;
            s += fmaxf(acc[mt][nt][1], 0.f) * w2v[nt].y;
            s += fmaxf(acc[mt][nt][2], 0.f) * w2v[nt].z;
            s += fmaxf(acc[mt][nt][3], 0.f) * w2v[nt].w;
        }
        s += __shfl_down(s, 32);
        s += __shfl_down(s, 16);
        if (lane < 16) atomicAdd(&outp[m0 + wm + mt * 16 + lane], s);
    }
}

extern "C" void kernel_launch(void* const* d_in, const int* in_sizes, int n_in,
                              void* d_out, int out_size, void* d_ws, size_t ws_size,
                              hipStream_t stream) {
    const float* x      = (const float*)d_in[0];
    const int*   types  = (const int*)d_in[1];
    const float* W_pre  = (const float*)d_in[2];
    const float* W_types= (const float*)d_in[3];
    const float* W_c1   = (const float*)d_in[4];
    const float* W_c2   = (const float*)d_in[5];
    float* out = (float*)d_out;

    // workspace layout (~90 MB):
    char* ws = (char*)d_ws;
    unsigned short* Xb  = (unsigned short*)(ws);                    // bf16 [32768][512], becomes X_res
    unsigned char*  Xff8= (unsigned char*)(ws + 33554432ull);       // fp8 [32768][1024] = 8*x_
    unsigned char*  Xb8 = (unsigned char*)(ws + 67108864ull);       // fp8 [32768][512] = x
    unsigned char*  Wp8 = (unsigned char*)(ws + 83886080ull);       // fp8 [1024][512] (x64)
    unsigned char*  Wt8 = (unsigned char*)(ws + 84410368ull);       // fp8 [8][512][1024] (x64)
    unsigned short* WcT = (unsigned short*)(ws + 88604672ull);      // bf16 [512][512]
    int* perm           = (int*)(ws + 89128960ull);                  // MPAD ints
    int* cnt            = (int*)(ws + 89264128ull);                  // cnt[8], fill2 = cnt+8
    int* fill2          = cnt + 8;

    prep_weights_kernel<<<dim3(32, 32, 10), dim3(32, 8), 0, stream>>>(
        W_pre, W_types, W_c1, Wp8, Wt8, WcT, cnt);
    prep_tokens_kernel<<<N_TOK * DIN / 1024, 256, 0, stream>>>(x, Xb, Xb8, types, cnt, perm);
    scatter_kernel<<<N_TOK / 256, 256, 0, stream>>>(types, cnt, fill2, perm, out);

    // GEMM1 (fp8): Xff8 = fp8(8 * relu(x @ W_pre))   [32768,512]x[512,1024]
    gemm_fp8_kernel<0><<<dim3(DFF / 128, N_TOK / 128), 256, 0, stream>>>(
        Xb8, Wp8, Xff8, nullptr, nullptr, nullptr, 512, 512);
    // GEMM2 (fp8, routed): Xb = bf16(Xb + relu(Xff8[perm] @ Wt8[bucket]) / 512)
    gemm_fp8_kernel<1><<<dim3(DIN / 128, MPAD / 128), 256, 0, stream>>>(
        Xff8, Wt8, Xb, Xb, perm, cnt, 1024, 1024);
    // GEMM3 + head (bf16): out = relu(Xb @ W_c1) @ W_c2
    gemm3_kernel<<<dim3(DIN / 256, N_TOK / 128), 512, 0, stream>>>(
        Xb, WcT, W_c2, out, 512, 512);
}

// Round 8
// 276.711 us; speedup vs baseline: 1.1735x; 1.1735x over previous
//
#include <hip/hip_runtime.h>
#include <stdint.h>

// Problem constants (B=64, S=512 -> 32768 tokens)
#define N_TOK 32768
#define DIN   512
#define DFF   1024
#define MPAD  33792   // 32768 + 8*128 worst-case bucket padding

// fp8 rotation convention: within each 128B K-window, row data is rotated by
// (row mod 16)*8 bytes: phys = (k & ~127) + (((k&127) + (row&15)*8) & 127).
// Same permutation on A-rows and B-rows => dot product unchanged. Staging is
// then a linear aligned copy; fragment reads cover all 32 banks (conflict-free).
__device__ __forceinline__ int rotk(int k, int row) {
    return (k & ~127) + (((k & 127) + ((row & 15) << 3)) & 127);
}

typedef __attribute__((ext_vector_type(8))) short bf16x8;
typedef __attribute__((ext_vector_type(4))) float f32x4;

__device__ __forceinline__ unsigned short f2bf(float f) {
    union { float f; unsigned int u; } v; v.f = f;
    unsigned int u = v.u;
    return (unsigned short)((u + 0x7FFFu + ((u >> 16) & 1u)) >> 16);
}
__device__ __forceinline__ float bf2f(unsigned int bits) {
    union { unsigned int u; float f; } v; v.u = bits << 16; return v.f;
}
// pack 4 floats -> 4 OCP e4m3 bytes (hw cvt, saturating)
__device__ __forceinline__ unsigned int pk4_fp8(float a, float b, float c, float d) {
    int v = __builtin_amdgcn_cvt_pk_fp8_f32(a, b, 0, false);
    v = __builtin_amdgcn_cvt_pk_fp8_f32(c, d, v, true);
    return (unsigned int)v;
}
__device__ __forceinline__ unsigned char f2fp8(float a) {
    return (unsigned char)(__builtin_amdgcn_cvt_pk_fp8_f32(a, a, 0, false) & 0xFF);
}

// async 16B global -> LDS (wave-uniform LDS base + lane*16 pattern)
__device__ __forceinline__ void async16(const void* g, void* l) {
    __builtin_amdgcn_global_load_lds(
        (const __attribute__((address_space(1))) void*)g,
        (__attribute__((address_space(3))) void*)l, 16, 0, 0);
}

// ---------------- fused weight prep ----------------
// z=0: W_pre [512][1024] -> Wp8 [1024][512] fp8 (x64, k-rotated)
// z=1..8: W_types[z-1] [1024][512] -> Wt8 [512][1024] fp8 (x64, k-rotated)
// z=9: W_c1 [512][512] -> WcT bf16 [512][512] (plain)
// also zeroes cnt[0..7] and fill2 (=cnt[8..15])
__global__ void prep_weights_kernel(const float* __restrict__ Wp,
                                    const float* __restrict__ Wt,
                                    const float* __restrict__ Wc,
                                    unsigned char* __restrict__ Wp8,
                                    unsigned char* __restrict__ Wt8,
                                    unsigned short* __restrict__ WcT,
                                    int* __restrict__ cnt) {
    __shared__ float tile[32][33];
    const int z = blockIdx.z;
    if (z == 0 && blockIdx.x == 0 && blockIdx.y == 0 &&
        threadIdx.y == 0 && threadIdx.x < 16)
        cnt[threadIdx.x] = 0;
    const float* s; int K, N;
    if (z == 0)      { s = Wp;                          K = 512;  N = 1024; }
    else if (z <= 8) { s = Wt + (size_t)(z-1)*DIN*DFF;  K = 1024; N = 512; }
    else             { s = Wc;                          K = 512;  N = 512; }
    const int n0 = blockIdx.x * 32, k0 = blockIdx.y * 32;
    if (n0 >= N || k0 >= K) return;
    for (int i = threadIdx.y; i < 32; i += 8)
        tile[i][threadIdx.x] = s[(size_t)(k0 + i) * N + n0 + threadIdx.x];
    __syncthreads();
    if (z == 0) {
        for (int i = threadIdx.y; i < 32; i += 8) {
            int n = n0 + i;
            Wp8[(size_t)n * K + rotk(k0 + threadIdx.x, n)] = f2fp8(tile[threadIdx.x][i] * 64.f);
        }
    } else if (z <= 8) {
        unsigned char* d = Wt8 + (size_t)(z-1)*DIN*DFF;
        for (int i = threadIdx.y; i < 32; i += 8) {
            int n = n0 + i;
            d[(size_t)n * K + rotk(k0 + threadIdx.x, n)] = f2fp8(tile[threadIdx.x][i] * 64.f);
        }
    } else {
        for (int i = threadIdx.y; i < 32; i += 8)
            WcT[(size_t)(n0 + i) * K + k0 + threadIdx.x] = f2bf(tile[threadIdx.x][i]);
    }
}

// ------- fused token prep: x -> bf16 Xb + fp8 Xb8 (rotated), histogram, perm init
// perm init lives HERE (strictly before scatter's writes) to avoid the
// same-kernel init/write race that broke round 7.
__global__ void prep_tokens_kernel(const float* __restrict__ x,
                                   unsigned short* __restrict__ Xb,
                                   unsigned char* __restrict__ Xb8,
                                   const int* __restrict__ types,
                                   int* __restrict__ cnt,
                                   int* __restrict__ perm) {
    __shared__ int lc[8];
    const int blk = blockIdx.x, tid = threadIdx.x;
    const int i = blk * 1024 + tid * 4;
    float4 v = *(const float4*)(x + i);
    ushort4 o;
    o.x = f2bf(v.x); o.y = f2bf(v.y); o.z = f2bf(v.z); o.w = f2bf(v.w);
    *(ushort4*)(Xb + i) = o;
    const int row = i >> 9;                 // DIN=512
    const int k   = i & 511;                // 4-aligned; rotation is 8-aligned -> no straddle
    *(unsigned int*)(Xb8 + (size_t)row * DIN + rotk(k, row)) = pk4_fp8(v.x, v.y, v.z, v.w);
    if (blk < 64) {
        if (tid < 8) lc[tid] = 0;
        __syncthreads();
        atomicAdd(&lc[types[blk * 512 + tid]], 1);
        atomicAdd(&lc[types[blk * 512 + 256 + tid]], 1);
        __syncthreads();
        if (tid < 8) atomicAdd(&cnt[tid], lc[tid]);
    } else if (blk < 64 + MPAD / 256) {
        perm[(blk - 64) * 256 + tid] = -1;
    }
}

// scatter: perm[bucketpos]=tok, invperm[tok]=bucketpos; zero out[]
__global__ void scatter_kernel(const int* __restrict__ types,
                               const int* __restrict__ cnt,
                               int* __restrict__ fill2,
                               int* __restrict__ perm,
                               int* __restrict__ invperm,
                               float* __restrict__ outz) {
    int i = blockIdx.x * 256 + threadIdx.x;      // grid exactly covers N_TOK
    outz[i] = 0.f;
    int pob[8]; int off = 0;
    #pragma unroll
    for (int b = 0; b < 8; b++) { pob[b] = off; off += ((cnt[b] + 127) >> 7) << 7; }
    int lane = threadIdx.x & 63;
    unsigned long long lt = (1ull << lane) - 1ull;
    int t = types[i];
    #pragma unroll
    for (int b = 0; b < 8; b++) {
        unsigned long long m = __ballot(t == b);
        if (t == b) {
            int leader = __ffsll((unsigned long long)m) - 1;
            int base = 0;
            if (lane == leader) base = atomicAdd(&fill2[b], __popcll(m));
            base = __shfl(base, leader);
            int p = pob[b] + base + __popcll(m & lt);
            perm[p] = i;
            invperm[i] = p;
        }
    }
}

// ---------- fp8 GEMM: 128x128 tile, BK=128, 256 thr / 4 waves, 16x16x32 fp8 -----
// Global fp8 data is k-rotated per row (see rotk); staging is a LINEAR aligned
// copy (LDS row stride 128B). Fragment read: 8B at (ks*32+quad*8+tl*8)&127 ->
// quarter-wave covers all 32 banks once: conflict-free.
// D[n][tok] via swapped operands: n = quad*4+reg, tok = lane&15.
// MODE 0 (GEMM1): A=Xb8 token-order; C = fp8(relu(acc)*0.125) scattered to
//                 bucket position p=invperm[tok], k-rotated by p.
// MODE 1 (GEMM2): A=Xff8 bucket-order (contiguous); B per bucket (prefix from
//                 cnt); epilogue via perm: Xb[tok] = bf16(Xb[tok]+relu(acc)/512)
template <int MODE>
__global__ __launch_bounds__(256, 4)
void gemm_fp8_kernel(const unsigned char* __restrict__ A,
                     const unsigned char* __restrict__ B,
                     void* __restrict__ Cout,
                     const unsigned short* __restrict__ xres,
                     const int* __restrict__ perm,
                     const int* __restrict__ invperm,
                     const int* __restrict__ cnt,
                     int K, int ldA) {
    __shared__ unsigned char As[128 * 128];
    __shared__ unsigned char Bs[128 * 128];
    __shared__ int ptile[128];

    const int tid  = threadIdx.x;
    const int wave = tid >> 6;
    const int lane = tid & 63;
    const int quad = lane >> 4;
    const int tl   = lane & 15;
    const int m0 = blockIdx.y * 128;
    const int n0 = blockIdx.x * 128;
    const int wm = (wave & 1) * 64;
    const int wn = (wave >> 1) * 64;

    const unsigned char* Bp = B;
    if constexpr (MODE == 1) {
        int bsel = 0, total = 0;
        #pragma unroll
        for (int i = 0; i < 8; i++) {
            if (i > 0 && m0 >= total) bsel = i;   // total == po[i] at loop top
            total += ((cnt[i] + 127) >> 7) << 7;
        }
        if (m0 >= total) return;                  // fully-padded tail block
        Bp = B + (size_t)bsel * (DIN * DFF);
        if (tid < 128) ptile[tid] = perm[m0 + tid];           // for epilogue only
    } else {
        if (tid < 128) ptile[tid] = invperm[m0 + tid];        // scatter positions
    }

    f32x4 acc[4][4];
    #pragma unroll
    for (int i = 0; i < 4; i++)
        #pragma unroll
        for (int j = 0; j < 4; j++)
            acc[i][j] = (f32x4){0.f, 0.f, 0.f, 0.f};

    for (int k0 = 0; k0 < K; k0 += 128) {
        __syncthreads();
        // A tile [128][128]: 1024 x 16B chunks, 4/thread, LINEAR copy
        #pragma unroll
        for (int i = 0; i < 4; i++) {
            const int c   = (i * 4 + wave) * 64 + lane;
            const int row = c >> 3;
            const int j   = c & 7;
            async16(A + (size_t)(m0 + row) * ldA + k0 + j * 16, (char*)As + (size_t)c * 16);
        }
        // B tile [128][128], linear
        #pragma unroll
        for (int i = 0; i < 4; i++) {
            const int c   = (i * 4 + wave) * 64 + lane;
            const int row = c >> 3;
            const int j   = c & 7;
            async16(Bp + (size_t)(n0 + row) * K + k0 + j * 16, (char*)Bs + (size_t)c * 16);
        }
        __syncthreads();

        #pragma unroll
        for (int ks = 0; ks < 4; ks++) {
            long af[4], bfr[4];
            const int o = (ks * 32 + quad * 8 + tl * 8) & 127;  // rotated frag offset
            #pragma unroll
            for (int t = 0; t < 4; t++)
                af[t] = *(const long*)(As + (wm + t * 16 + tl) * 128 + o);
            #pragma unroll
            for (int t = 0; t < 4; t++)
                bfr[t] = *(const long*)(Bs + (wn + t * 16 + tl) * 128 + o);
            #pragma unroll
            for (int mt = 0; mt < 4; mt++)
                #pragma unroll
                for (int nt = 0; nt < 4; nt++)
                    acc[mt][nt] = __builtin_amdgcn_mfma_f32_16x16x32_fp8_fp8(
                        bfr[nt], af[mt], acc[mt][nt], 0, 0, 0);  // swapped: D[n][tok]
        }
    }

    // epilogue: lane holds 4 consecutive n (regs) for token tl
    if constexpr (MODE == 0) {
        unsigned char* C8 = (unsigned char*)Cout;
        #pragma unroll
        for (int mt = 0; mt < 4; mt++) {
            const int p = ptile[wm + mt * 16 + tl];            // bucket position
            const size_t rowbase = (size_t)p * DFF;
            #pragma unroll
            for (int nt = 0; nt < 4; nt++) {
                const int off = wn + nt * 16 + quad * 4;       // in-window offset
                unsigned int pk = pk4_fp8(fmaxf(acc[mt][nt][0], 0.f) * 0.125f,
                                          fmaxf(acc[mt][nt][1], 0.f) * 0.125f,
                                          fmaxf(acc[mt][nt][2], 0.f) * 0.125f,
                                          fmaxf(acc[mt][nt][3], 0.f) * 0.125f);
                const int phys = (off & ~127) + (((off & 127) + ((p & 15) << 3)) & 127);
                *(unsigned int*)(C8 + rowbase + n0 + phys) = pk;
            }
        }
    } else {
        unsigned short* Cb = (unsigned short*)Cout;
        #pragma unroll
        for (int mt = 0; mt < 4; mt++) {
            int tok = ptile[wm + mt * 16 + tl];
            if (tok < 0) continue;
            const size_t rowbase = (size_t)tok * DIN;
            #pragma unroll
            for (int nt = 0; nt < 4; nt++) {
                const int ncol = n0 + wn + nt * 16 + quad * 4;
                ushort4 rv = *(const ushort4*)(xres + rowbase + ncol);
                ushort4 o;
                o.x = f2bf(bf2f(rv.x) + fmaxf(acc[mt][nt][0], 0.f) * 0.001953125f);
                o.y = f2bf(bf2f(rv.y) + fmaxf(acc[mt][nt][1], 0.f) * 0.001953125f);
                o.z = f2bf(bf2f(rv.z) + fmaxf(acc[mt][nt][2], 0.f) * 0.001953125f);
                o.w = f2bf(bf2f(rv.w) + fmaxf(acc[mt][nt][3], 0.f) * 0.001953125f);
                *(ushort4*)(Cb + rowbase + ncol) = o;
            }
        }
    }
}

// ------- bf16 GEMM3 + head (kept full precision): 128x256 tile, 512 thr --------
// out[tok] += relu(Xb @ W_c1) . w2   (atomicAdd partials per n-block)
__global__ __launch_bounds__(512, 4)
void gemm3_kernel(const unsigned short* __restrict__ A,
                  const unsigned short* __restrict__ B,
                  const float* __restrict__ w2,
                  float* __restrict__ outp,
                  int K, int ldA) {
    __shared__ unsigned short As[128 * 64];
    __shared__ unsigned short Bs[256 * 64];

    const int tid  = threadIdx.x;
    const int wave = tid >> 6;
    const int lane = tid & 63;
    const int quad = lane >> 4;
    const int tl   = lane & 15;
    const int m0 = blockIdx.y * 128;
    const int n0 = blockIdx.x * 256;
    const int wm = (wave & 1) * 64;
    const int wn = (wave >> 1) * 64;

    f32x4 acc[4][4];
    #pragma unroll
    for (int i = 0; i < 4; i++)
        #pragma unroll
        for (int j = 0; j < 4; j++)
            acc[i][j] = (f32x4){0.f, 0.f, 0.f, 0.f};

    for (int k0 = 0; k0 < K; k0 += 64) {
        __syncthreads();
        #pragma unroll
        for (int i = 0; i < 2; i++) {
            const int c   = (i * 8 + wave) * 64 + lane;
            const int row = c >> 3;
            const int gj  = (c & 7) ^ (row & 7);
            async16(A + (size_t)(m0 + row) * ldA + k0 + gj * 8, (char*)As + (size_t)c * 16);
        }
        #pragma unroll
        for (int i = 0; i < 4; i++) {
            const int c   = (i * 8 + wave) * 64 + lane;
            const int row = c >> 3;
            const int gj  = (c & 7) ^ (row & 7);
            async16(B + (size_t)(n0 + row) * K + k0 + gj * 8, (char*)Bs + (size_t)c * 16);
        }
        __syncthreads();

        #pragma unroll
        for (int ks = 0; ks < 2; ks++) {
            bf16x8 af[4], bfr[4];
            const int jc = ks * 4 + quad;
            #pragma unroll
            for (int t = 0; t < 4; t++) {
                const int r = wm + t * 16 + tl;
                af[t] = *(const bf16x8*)(As + (r * 8 + (jc ^ (r & 7))) * 8);
            }
            #pragma unroll
            for (int t = 0; t < 4; t++) {
                const int r = wn + t * 16 + tl;
                bfr[t] = *(const bf16x8*)(Bs + (r * 8 + (jc ^ (r & 7))) * 8);
            }
            #pragma unroll
            for (int mt = 0; mt < 4; mt++)
                #pragma unroll
                for (int nt = 0; nt < 4; nt++)
                    acc[mt][nt] = __builtin_amdgcn_mfma_f32_16x16x32_bf16(
                        bfr[nt], af[mt], acc[mt][nt], 0, 0, 0);
        }
    }

    float4 w2v[4];
    #pragma unroll
    for (int nt = 0; nt < 4; nt++)
        w2v[nt] = *(const float4*)(w2 + n0 + wn + nt * 16 + quad * 4);
    #pragma unroll
    for (int mt = 0; mt < 4; mt++) {
        float s = 0.f;
        #pragma unroll
        for (int nt = 0; nt < 4; nt++) {
            s += fmaxf(acc[mt][nt][0], 0.f) * w2v[nt].x;
            s += fmaxf(acc[mt][nt][1], 0.f) * w2v[nt].y;
            s += fmaxf(acc[mt][nt][2], 0.f) * w2v[nt].z;
            s += fmaxf(acc[mt][nt][3], 0.f) * w2v[nt].w;
        }
        s += __shfl_down(s, 32);
        s += __shfl_down(s, 16);
        if (lane < 16) atomicAdd(&outp[m0 + wm + mt * 16 + lane], s);
    }
}

extern "C" void kernel_launch(void* const* d_in, const int* in_sizes, int n_in,
                              void* d_out, int out_size, void* d_ws, size_t ws_size,
                              hipStream_t stream) {
    const float* x      = (const float*)d_in[0];
    const int*   types  = (const int*)d_in[1];
    const float* W_pre  = (const float*)d_in[2];
    const float* W_types= (const float*)d_in[3];
    const float* W_c1   = (const float*)d_in[4];
    const float* W_c2   = (const float*)d_in[5];
    float* out = (float*)d_out;

    // workspace layout (~91 MB):
    char* ws = (char*)d_ws;
    unsigned short* Xb  = (unsigned short*)(ws);                    // bf16 [32768][512], becomes X_res
    unsigned char*  Xff8= (unsigned char*)(ws + 33554432ull);       // fp8 [MPAD][1024] = 8*x_, bucket order, k-rotated
    unsigned char*  Xb8 = (unsigned char*)(ws + 68157440ull);       // fp8 [32768][512] = x, k-rotated
    unsigned char*  Wp8 = (unsigned char*)(ws + 84934656ull);       // fp8 [1024][512] (x64, rotated)
    unsigned char*  Wt8 = (unsigned char*)(ws + 85458944ull);       // fp8 [8][512][1024] (x64, rotated)
    unsigned short* WcT = (unsigned short*)(ws + 89653248ull);      // bf16 [512][512]
    int* perm           = (int*)(ws + 90177536ull);                  // MPAD ints
    int* invperm        = (int*)(ws + 90312704ull);                  // N_TOK ints
    int* cnt            = (int*)(ws + 90443776ull);                  // cnt[8], fill2 = cnt+8
    int* fill2          = cnt + 8;

    prep_weights_kernel<<<dim3(32, 32, 10), dim3(32, 8), 0, stream>>>(
        W_pre, W_types, W_c1, Wp8, Wt8, WcT, cnt);
    prep_tokens_kernel<<<N_TOK * DIN / 1024, 256, 0, stream>>>(x, Xb, Xb8, types, cnt, perm);
    scatter_kernel<<<N_TOK / 256, 256, 0, stream>>>(types, cnt, fill2, perm, invperm, out);

    // GEMM1 (fp8): Xff8[invperm[tok]] = fp8(8 * relu(x @ W_pre))  (bucket order)
    gemm_fp8_kernel<0><<<dim3(DFF / 128, N_TOK / 128), 256, 0, stream>>>(
        Xb8, Wp8, Xff8, nullptr, nullptr, invperm, cnt, 512, 512);
    // GEMM2 (fp8, routed, contiguous A): Xb = bf16(Xb + relu(Xff8 @ Wt8[bucket]) / 512)
    gemm_fp8_kernel<1><<<dim3(DIN / 128, MPAD / 128), 256, 0, stream>>>(
        Xff8, Wt8, Xb, Xb, perm, nullptr, cnt, 1024, 1024);
    // GEMM3 + head (bf16): out = relu(Xb @ W_c1) @ W_c2
    gemm3_kernel<<<dim3(DIN / 256, N_TOK / 128), 512, 0, stream>>>(
        Xb, WcT, W_c2, out, 512, 512);
}

// Round 9
// 235.415 us; speedup vs baseline: 1.3794x; 1.1754x over previous
//
#include <hip/hip_runtime.h>
#include <stdint.h>

// Problem constants (B=64, S=512 -> 32768 tokens)
#define N_TOK 32768
#define DIN   512
#define DFF   1024
#define MPAD  33792   // 32768 + 8*128 worst-case bucket padding

// fp8 rotation convention: within each 128B K-window, row data is rotated by
// (row mod 16)*8 bytes: phys = (k & ~127) + (((k&127) + (row&15)*8) & 127).
// Same permutation on A-rows and B-rows => dot product unchanged. Staging is
// then a linear aligned copy; fragment reads cover all 32 banks (conflict-free).
__device__ __forceinline__ int rotk(int k, int row) {
    return (k & ~127) + (((k & 127) + ((row & 15) << 3)) & 127);
}

typedef __attribute__((ext_vector_type(8))) short bf16x8;
typedef __attribute__((ext_vector_type(4))) float f32x4;

__device__ __forceinline__ unsigned short f2bf(float f) {
    union { float f; unsigned int u; } v; v.f = f;
    unsigned int u = v.u;
    return (unsigned short)((u + 0x7FFFu + ((u >> 16) & 1u)) >> 16);
}
__device__ __forceinline__ float bf2f(unsigned int bits) {
    union { unsigned int u; float f; } v; v.u = bits << 16; return v.f;
}
// pack 4 floats -> 4 OCP e4m3 bytes (hw cvt, saturating)
__device__ __forceinline__ unsigned int pk4_fp8(float a, float b, float c, float d) {
    int v = __builtin_amdgcn_cvt_pk_fp8_f32(a, b, 0, false);
    v = __builtin_amdgcn_cvt_pk_fp8_f32(c, d, v, true);
    return (unsigned int)v;
}
__device__ __forceinline__ unsigned char f2fp8(float a) {
    return (unsigned char)(__builtin_amdgcn_cvt_pk_fp8_f32(a, a, 0, false) & 0xFF);
}

// async 16B global -> LDS (wave-uniform LDS base + lane*16 pattern)
__device__ __forceinline__ void async16(const void* g, void* l) {
    __builtin_amdgcn_global_load_lds(
        (const __attribute__((address_space(1))) void*)g,
        (__attribute__((address_space(3))) void*)l, 16, 0, 0);
}

// ---------------- fused weight prep ----------------
// z=0: W_pre [512][1024] -> Wp8 [1024][512] fp8 (x64, k-rotated)
// z=1..8: W_types[z-1] [1024][512] -> Wt8 [512][1024] fp8 (x64, k-rotated)
// z=9: W_c1 [512][512] -> WcT bf16 [512][512] (plain)
// also zeroes cnt[0..7]
__global__ void prep_weights_kernel(const float* __restrict__ Wp,
                                    const float* __restrict__ Wt,
                                    const float* __restrict__ Wc,
                                    unsigned char* __restrict__ Wp8,
                                    unsigned char* __restrict__ Wt8,
                                    unsigned short* __restrict__ WcT,
                                    int* __restrict__ cnt) {
    __shared__ float tile[32][33];
    const int z = blockIdx.z;
    if (z == 0 && blockIdx.x == 0 && blockIdx.y == 0 &&
        threadIdx.y == 0 && threadIdx.x < 8)
        cnt[threadIdx.x] = 0;
    const float* s; int K, N;
    if (z == 0)      { s = Wp;                          K = 512;  N = 1024; }
    else if (z <= 8) { s = Wt + (size_t)(z-1)*DIN*DFF;  K = 1024; N = 512; }
    else             { s = Wc;                          K = 512;  N = 512; }
    const int n0 = blockIdx.x * 32, k0 = blockIdx.y * 32;
    if (n0 >= N || k0 >= K) return;
    for (int i = threadIdx.y; i < 32; i += 8)
        tile[i][threadIdx.x] = s[(size_t)(k0 + i) * N + n0 + threadIdx.x];
    __syncthreads();
    if (z == 0) {
        for (int i = threadIdx.y; i < 32; i += 8) {
            int n = n0 + i;
            Wp8[(size_t)n * K + rotk(k0 + threadIdx.x, n)] = f2fp8(tile[threadIdx.x][i] * 64.f);
        }
    } else if (z <= 8) {
        unsigned char* d = Wt8 + (size_t)(z-1)*DIN*DFF;
        for (int i = threadIdx.y; i < 32; i += 8) {
            int n = n0 + i;
            d[(size_t)n * K + rotk(k0 + threadIdx.x, n)] = f2fp8(tile[threadIdx.x][i] * 64.f);
        }
    } else {
        for (int i = threadIdx.y; i < 32; i += 8)
            WcT[(size_t)(n0 + i) * K + k0 + threadIdx.x] = f2bf(tile[threadIdx.x][i]);
    }
}

// ------- fused token prep: x -> bf16 Xb + fp8 Xb8 (rotated), histogram ---------
// blocks 0..63 histogram tokens [blk*512, blk*512+512) -> cnt (global total) AND
// blockhist[blk][8] (per-block counts for the atomic-free scatter).
__global__ void prep_tokens_kernel(const float* __restrict__ x,
                                   unsigned short* __restrict__ Xb,
                                   unsigned char* __restrict__ Xb8,
                                   const int* __restrict__ types,
                                   int* __restrict__ cnt,
                                   int* __restrict__ blockhist) {
    __shared__ int lc[8];
    const int blk = blockIdx.x, tid = threadIdx.x;
    const int i = blk * 1024 + tid * 4;
    float4 v = *(const float4*)(x + i);
    ushort4 o;
    o.x = f2bf(v.x); o.y = f2bf(v.y); o.z = f2bf(v.z); o.w = f2bf(v.w);
    *(ushort4*)(Xb + i) = o;
    const int row = i >> 9;                 // DIN=512
    const int k   = i & 511;                // 4-aligned; rotation is 8-aligned -> no straddle
    *(unsigned int*)(Xb8 + (size_t)row * DIN + rotk(k, row)) = pk4_fp8(v.x, v.y, v.z, v.w);
    if (blk < 64) {
        if (tid < 8) lc[tid] = 0;
        __syncthreads();
        atomicAdd(&lc[types[blk * 512 + tid]], 1);
        atomicAdd(&lc[types[blk * 512 + 256 + tid]], 1);
        __syncthreads();
        if (tid < 8) {
            atomicAdd(&cnt[tid], lc[tid]);
            blockhist[blk * 8 + tid] = lc[tid];
        }
    }
}

// ---- atomic-free scatter: 64 blocks x 512 threads, deterministic placement ----
// base[t] = padded-prefix(cnt)[t] + sum_{j<blk} blockhist[j][t]; intra-block
// rank via LDS atomics only. perm[p]=tok, invperm[tok]=p, pad entries stay -1
// (perm init done below in this kernel's unused lanes? no: pad rows only exist
// past N_TOK; init them here from block 63's tail threads is racy -> init perm
// pads in prep via memset-like: we instead init ALL of perm here first? No --
// pads are perm[po[b]+cnt[b] .. po[b+1]): each block only writes real entries,
// so pads must be pre-initialized: done by prep_tokens? Simpler: scatter also
// writes pads: block 63 (last) can't know... -> dedicated: threads with
// i >= N_TOK impossible (grid=N_TOK). Pads initialized via separate sweep in
// prep (kept from r8): see prep_pad flag below.
__global__ void scatter_kernel(const int* __restrict__ types,
                               const int* __restrict__ cnt,
                               const int* __restrict__ blockhist,
                               int* __restrict__ perm,
                               int* __restrict__ invperm,
                               float* __restrict__ outz) {
    __shared__ int base[8];
    __shared__ int fill[8];
    const int blk = blockIdx.x;            // 64
    const int tid = threadIdx.x;           // 512
    const int i = blk * 512 + tid;
    outz[i] = 0.f;
    if (tid < 8) {
        int off = 0, pob = 0;
        #pragma unroll
        for (int b = 0; b < 8; b++) {
            if (b == tid) pob = off;
            off += ((cnt[b] + 127) >> 7) << 7;
        }
        int pre = 0;
        for (int j = 0; j < blk; j++) pre += blockhist[j * 8 + tid];
        base[tid] = pob + pre;
        fill[tid] = 0;
    }
    __syncthreads();
    const int t = types[i];
    const int r = atomicAdd(&fill[t], 1);  // LDS atomic: intra-block rank
    const int p = base[t] + r;
    perm[p] = i;
    invperm[i] = p;
}

// pad-init for perm: small sweep (runs before scatter)
__global__ void perm_pad_kernel(int* __restrict__ perm) {
    perm[blockIdx.x * 256 + threadIdx.x] = -1;
}

// ---------- fp8 GEMM: 128x128 tile, BK=128, 256 thr / 4 waves, 16x16x32 fp8 -----
// Global fp8 data is k-rotated per row (see rotk); staging is a LINEAR aligned
// copy (LDS row stride 128B). Fragment read: 8B at (ks*32+quad*8+tl*8)&127 ->
// quarter-wave covers all 32 banks once: conflict-free.
// D[n][tok] via swapped operands: n = quad*4+reg, tok = lane&15.
// MODE 0 (GEMM1): A=Xb8 token-order; C = fp8(relu(acc)*0.125) scattered to
//                 bucket position p=invperm[tok], k-rotated by p.
// MODE 1 (GEMM2): A=Xff8 bucket-order (contiguous); B per bucket (prefix from
//                 cnt); epilogue via perm: Xb[tok] = bf16(Xb[tok]+relu(acc)/512)
template <int MODE>
__global__ __launch_bounds__(256, 4)
void gemm_fp8_kernel(const unsigned char* __restrict__ A,
                     const unsigned char* __restrict__ B,
                     void* __restrict__ Cout,
                     const unsigned short* __restrict__ xres,
                     const int* __restrict__ perm,
                     const int* __restrict__ invperm,
                     const int* __restrict__ cnt,
                     int K, int ldA) {
    __shared__ unsigned char As[128 * 128];
    __shared__ unsigned char Bs[128 * 128];
    __shared__ int ptile[128];

    const int tid  = threadIdx.x;
    const int wave = tid >> 6;
    const int lane = tid & 63;
    const int quad = lane >> 4;
    const int tl   = lane & 15;
    const int m0 = blockIdx.y * 128;
    const int n0 = blockIdx.x * 128;
    const int wm = (wave & 1) * 64;
    const int wn = (wave >> 1) * 64;

    const unsigned char* Bp = B;
    if constexpr (MODE == 1) {
        int bsel = 0, total = 0;
        #pragma unroll
        for (int i = 0; i < 8; i++) {
            if (i > 0 && m0 >= total) bsel = i;   // total == po[i] at loop top
            total += ((cnt[i] + 127) >> 7) << 7;
        }
        if (m0 >= total) return;                  // fully-padded tail block
        Bp = B + (size_t)bsel * (DIN * DFF);
        if (tid < 128) ptile[tid] = perm[m0 + tid];           // for epilogue only
    } else {
        if (tid < 128) ptile[tid] = invperm[m0 + tid];        // scatter positions
    }

    f32x4 acc[4][4];
    #pragma unroll
    for (int i = 0; i < 4; i++)
        #pragma unroll
        for (int j = 0; j < 4; j++)
            acc[i][j] = (f32x4){0.f, 0.f, 0.f, 0.f};

    for (int k0 = 0; k0 < K; k0 += 128) {
        __syncthreads();
        // A tile [128][128]: 1024 x 16B chunks, 4/thread, LINEAR copy
        #pragma unroll
        for (int i = 0; i < 4; i++) {
            const int c   = (i * 4 + wave) * 64 + lane;
            const int row = c >> 3;
            const int j   = c & 7;
            async16(A + (size_t)(m0 + row) * ldA + k0 + j * 16, (char*)As + (size_t)c * 16);
        }
        // B tile [128][128], linear
        #pragma unroll
        for (int i = 0; i < 4; i++) {
            const int c   = (i * 4 + wave) * 64 + lane;
            const int row = c >> 3;
            const int j   = c & 7;
            async16(Bp + (size_t)(n0 + row) * K + k0 + j * 16, (char*)Bs + (size_t)c * 16);
        }
        __syncthreads();

        #pragma unroll
        for (int ks = 0; ks < 4; ks++) {
            long af[4], bfr[4];
            const int o = (ks * 32 + quad * 8 + tl * 8) & 127;  // rotated frag offset
            #pragma unroll
            for (int t = 0; t < 4; t++)
                af[t] = *(const long*)(As + (wm + t * 16 + tl) * 128 + o);
            #pragma unroll
            for (int t = 0; t < 4; t++)
                bfr[t] = *(const long*)(Bs + (wn + t * 16 + tl) * 128 + o);
            #pragma unroll
            for (int mt = 0; mt < 4; mt++)
                #pragma unroll
                for (int nt = 0; nt < 4; nt++)
                    acc[mt][nt] = __builtin_amdgcn_mfma_f32_16x16x32_fp8_fp8(
                        bfr[nt], af[mt], acc[mt][nt], 0, 0, 0);  // swapped: D[n][tok]
        }
    }

    // epilogue: lane holds 4 consecutive n (regs) for token tl
    if constexpr (MODE == 0) {
        unsigned char* C8 = (unsigned char*)Cout;
        #pragma unroll
        for (int mt = 0; mt < 4; mt++) {
            const int p = ptile[wm + mt * 16 + tl];            // bucket position
            const size_t rowbase = (size_t)p * DFF;
            #pragma unroll
            for (int nt = 0; nt < 4; nt++) {
                const int off = wn + nt * 16 + quad * 4;       // in-window offset
                unsigned int pk = pk4_fp8(fmaxf(acc[mt][nt][0], 0.f) * 0.125f,
                                          fmaxf(acc[mt][nt][1], 0.f) * 0.125f,
                                          fmaxf(acc[mt][nt][2], 0.f) * 0.125f,
                                          fmaxf(acc[mt][nt][3], 0.f) * 0.125f);
                const int phys = (off & ~127) + (((off & 127) + ((p & 15) << 3)) & 127);
                *(unsigned int*)(C8 + rowbase + n0 + phys) = pk;
            }
        }
    } else {
        unsigned short* Cb = (unsigned short*)Cout;
        #pragma unroll
        for (int mt = 0; mt < 4; mt++) {
            int tok = ptile[wm + mt * 16 + tl];
            if (tok < 0) continue;
            const size_t rowbase = (size_t)tok * DIN;
            #pragma unroll
            for (int nt = 0; nt < 4; nt++) {
                const int ncol = n0 + wn + nt * 16 + quad * 4;
                ushort4 rv = *(const ushort4*)(xres + rowbase + ncol);
                ushort4 o;
                o.x = f2bf(bf2f(rv.x) + fmaxf(acc[mt][nt][0], 0.f) * 0.001953125f);
                o.y = f2bf(bf2f(rv.y) + fmaxf(acc[mt][nt][1], 0.f) * 0.001953125f);
                o.z = f2bf(bf2f(rv.z) + fmaxf(acc[mt][nt][2], 0.f) * 0.001953125f);
                o.w = f2bf(bf2f(rv.w) + fmaxf(acc[mt][nt][3], 0.f) * 0.001953125f);
                *(ushort4*)(Cb + rowbase + ncol) = o;
            }
        }
    }
}

// ------- bf16 GEMM3 + head (kept full precision): 128x256 tile, 512 thr --------
// out[tok] += relu(Xb @ W_c1) . w2   (atomicAdd partials per n-block)
__global__ __launch_bounds__(512, 4)
void gemm3_kernel(const unsigned short* __restrict__ A,
                  const unsigned short* __restrict__ B,
                  const float* __restrict__ w2,
                  float* __restrict__ outp,
                  int K, int ldA) {
    __shared__ unsigned short As[128 * 64];
    __shared__ unsigned short Bs[256 * 64];

    const int tid  = threadIdx.x;
    const int wave = tid >> 6;
    const int lane = tid & 63;
    const int quad = lane >> 4;
    const int tl   = lane & 15;
    const int m0 = blockIdx.y * 128;
    const int n0 = blockIdx.x * 256;
    const int wm = (wave & 1) * 64;
    const int wn = (wave >> 1) * 64;

    f32x4 acc[4][4];
    #pragma unroll
    for (int i = 0; i < 4; i++)
        #pragma unroll
        for (int j = 0; j < 4; j++)
            acc[i][j] = (f32x4){0.f, 0.f, 0.f, 0.f};

    for (int k0 = 0; k0 < K; k0 += 64) {
        __syncthreads();
        #pragma unroll
        for (int i = 0; i < 2; i++) {
            const int c   = (i * 8 + wave) * 64 + lane;
            const int row = c >> 3;
            const int gj  = (c & 7) ^ (row & 7);
            async16(A + (size_t)(m0 + row) * ldA + k0 + gj * 8, (char*)As + (size_t)c * 16);
        }
        #pragma unroll
        for (int i = 0; i < 4; i++) {
            const int c   = (i * 8 + wave) * 64 + lane;
            const int row = c >> 3;
            const int gj  = (c & 7) ^ (row & 7);
            async16(B + (size_t)(n0 + row) * K + k0 + gj * 8, (char*)Bs + (size_t)c * 16);
        }
        __syncthreads();

        #pragma unroll
        for (int ks = 0; ks < 2; ks++) {
            bf16x8 af[4], bfr[4];
            const int jc = ks * 4 + quad;
            #pragma unroll
            for (int t = 0; t < 4; t++) {
                const int r = wm + t * 16 + tl;
                af[t] = *(const bf16x8*)(As + (r * 8 + (jc ^ (r & 7))) * 8);
            }
            #pragma unroll
            for (int t = 0; t < 4; t++) {
                const int r = wn + t * 16 + tl;
                bfr[t] = *(const bf16x8*)(Bs + (r * 8 + (jc ^ (r & 7))) * 8);
            }
            #pragma unroll
            for (int mt = 0; mt < 4; mt++)
                #pragma unroll
                for (int nt = 0; nt < 4; nt++)
                    acc[mt][nt] = __builtin_amdgcn_mfma_f32_16x16x32_bf16(
                        bfr[nt], af[mt], acc[mt][nt], 0, 0, 0);
        }
    }

    float4 w2v[4];
    #pragma unroll
    for (int nt = 0; nt < 4; nt++)
        w2v[nt] = *(const float4*)(w2 + n0 + wn + nt * 16 + quad * 4);
    #pragma unroll
    for (int mt = 0; mt < 4; mt++) {
        float s = 0.f;
        #pragma unroll
        for (int nt = 0; nt < 4; nt++) {
            s += fmaxf(acc[mt][nt][0], 0.f) * w2v[nt].x;
            s += fmaxf(acc[mt][nt][1], 0.f) * w2v[nt].y;
            s += fmaxf(acc[mt][nt][2], 0.f) * w2v[nt].z;
            s += fmaxf(acc[mt][nt][3], 0.f) * w2v[nt].w;
        }
        s += __shfl_down(s, 32);
        s += __shfl_down(s, 16);
        if (lane < 16) atomicAdd(&outp[m0 + wm + mt * 16 + lane], s);
    }
}

extern "C" void kernel_launch(void* const* d_in, const int* in_sizes, int n_in,
                              void* d_out, int out_size, void* d_ws, size_t ws_size,
                              hipStream_t stream) {
    const float* x      = (const float*)d_in[0];
    const int*   types  = (const int*)d_in[1];
    const float* W_pre  = (const float*)d_in[2];
    const float* W_types= (const float*)d_in[3];
    const float* W_c1   = (const float*)d_in[4];
    const float* W_c2   = (const float*)d_in[5];
    float* out = (float*)d_out;

    // workspace layout (~91 MB):
    char* ws = (char*)d_ws;
    unsigned short* Xb  = (unsigned short*)(ws);                    // bf16 [32768][512], becomes X_res
    unsigned char*  Xff8= (unsigned char*)(ws + 33554432ull);       // fp8 [MPAD][1024] = 8*x_, bucket order, k-rotated
    unsigned char*  Xb8 = (unsigned char*)(ws + 68157440ull);       // fp8 [32768][512] = x, k-rotated
    unsigned char*  Wp8 = (unsigned char*)(ws + 84934656ull);       // fp8 [1024][512] (x64, rotated)
    unsigned char*  Wt8 = (unsigned char*)(ws + 85458944ull);       // fp8 [8][512][1024] (x64, rotated)
    unsigned short* WcT = (unsigned short*)(ws + 89653248ull);      // bf16 [512][512]
    int* perm           = (int*)(ws + 90177536ull);                  // MPAD ints
    int* invperm        = (int*)(ws + 90312704ull);                  // N_TOK ints
    int* cnt            = (int*)(ws + 90443776ull);                  // 8 ints
    int* blockhist      = cnt + 16;                                  // 64*8 ints

    prep_weights_kernel<<<dim3(32, 32, 10), dim3(32, 8), 0, stream>>>(
        W_pre, W_types, W_c1, Wp8, Wt8, WcT, cnt);
    perm_pad_kernel<<<MPAD / 256, 256, 0, stream>>>(perm);
    prep_tokens_kernel<<<N_TOK * DIN / 1024, 256, 0, stream>>>(x, Xb, Xb8, types, cnt, blockhist);
    scatter_kernel<<<64, 512, 0, stream>>>(types, cnt, blockhist, perm, invperm, out);

    // GEMM1 (fp8): Xff8[invperm[tok]] = fp8(8 * relu(x @ W_pre))  (bucket order)
    gemm_fp8_kernel<0><<<dim3(DFF / 128, N_TOK / 128), 256, 0, stream>>>(
        Xb8, Wp8, Xff8, nullptr, nullptr, invperm, cnt, 512, 512);
    // GEMM2 (fp8, routed, contiguous A): Xb = bf16(Xb + relu(Xff8 @ Wt8[bucket]) / 512)
    gemm_fp8_kernel<1><<<dim3(DIN / 128, MPAD / 128), 256, 0, stream>>>(
        Xff8, Wt8, Xb, Xb, perm, nullptr, cnt, 1024, 1024);
    // GEMM3 + head (bf16): out = relu(Xb @ W_c1) @ W_c2
    gemm3_kernel<<<dim3(DIN / 256, N_TOK / 128), 512, 0, stream>>>(
        Xb, WcT, W_c2, out, 512, 512);
}